// Round 5
// baseline (1613.696 us; speedup 1.0000x reference)
//
#include <hip/hip_runtime.h>

#define DZ 64
#define DX 32
#define DS 16
#define TT 1024
#define NS 1024

__device__ __forceinline__ float softplus_eps(float x) {
    // jax.nn.softplus = max(x,0) + log1p(exp(-|x|)); +1e-6
    return fmaxf(x, 0.f) + log1pf(expf(-fabsf(x))) + 1e-6f;
}

// ---------------- Phase 1: sequential z rollout ----------------
// 1024 waves, one per sim, lane = z-dim. Weights are staged into LDS once
// per block, then read per-lane into VGPRs. ds_read results are NOT
// rematerializable, so the allocator must keep Wrow/Crow register-resident
// (R2/R3 bug: invariant global loads were remat'd into the hot loop every
// step; VGPR_Count=60 proved nothing stayed resident). Hot loop: zero LDS,
// broadcast via v_readlane -> SGPR fma operands.
__global__ __launch_bounds__(256, 1) void plrnn_z_kernel(
    const float* __restrict__ u,   // (T, N, 16)
    const float* __restrict__ z0,  // (N, 64)
    const float* __restrict__ nz,  // (T, N, 64)
    const float* __restrict__ AW,  // (64, 64)
    const float* __restrict__ Cm,  // (64, 16)
    const float* __restrict__ Q,   // (64,)
    float* __restrict__ zo)        // (T, N, 64)
{
    const int tid  = threadIdx.x;
    const int lane = tid & 63;
    const int wv   = tid >> 6;
    const int sim  = __builtin_amdgcn_readfirstlane((int)((blockIdx.x << 2) | wv));

    __shared__ float AWl[DZ][DZ + 4];   // +4 pad softens one-time bank conflicts
    __shared__ float Cl[DZ][DS + 4];
    __shared__ float Ql[DZ];

    {   // stage weights: AW 16 floats/thread, C 4 floats/thread
        const int r = tid >> 2;
        const int c = (tid & 3) * 16;
        #pragma unroll
        for (int k = 0; k < 16; ++k) AWl[r][c + k] = AW[r * DZ + c + k];
        const int cc = (tid & 3) * 4;
        #pragma unroll
        for (int k = 0; k < 4; ++k) Cl[r][cc + k] = Cm[r * DS + cc + k];
        if (tid < DZ) Ql[tid] = Q[tid];
    }
    __syncthreads();

    // per-lane weights from LDS -> guaranteed VGPR-resident
    float Wrow[DZ];
    #pragma unroll
    for (int k = 0; k < DZ; ++k) Wrow[k] = AWl[lane][k];
    const float Ad = Wrow[lane & 63];          // runtime-indexed once (pre-loop)
    Wrow[lane] = 0.f;                          // zero diagonal
    float Crow[DS];
    #pragma unroll
    for (int s = 0; s < DS; ++s) Crow[s] = Cl[lane][s];
    const float qv = softplus_eps(Ql[lane]);

    float zl = z0[(size_t)sim * DZ + lane];

    const float*  pnz = nz + (size_t)sim * DZ + lane;
    const float4* pu  = (const float4*)(u + (size_t)sim * DS);  // wave-uniform -> s_load
    float*        pz  = zo + (size_t)sim * DZ + lane;

    const size_t snz = (size_t)NS * DZ;        // per-step element stride
    const size_t su4 = (size_t)NS * DS / 4;    // per-step float4 stride (u)

    // prefetch: nz depth 8, u depth 2
    float nzb[8];
    #pragma unroll
    for (int j = 0; j < 8; ++j) nzb[j] = pnz[(size_t)j * snz];
    float4 ub[2][4];
    #pragma unroll
    for (int j = 0; j < 2; ++j)
        #pragma unroll
        for (int q = 0; q < 4; ++q) ub[j][q] = pu[(size_t)j * su4 + q];

    for (int t0 = 0; t0 < TT; t0 += 8) {
        #pragma unroll
        for (int j = 0; j < 8; ++j) {
            const int t = t0 + j;
            const float vnz = nzb[j];

            // emit z_t (carry BEFORE update; z[0] == z0)
            pz[(size_t)t * snz] = zl;

            const int rzb = __float_as_int(fmaxf(zl, 0.f));

            float m0 = Ad * zl, m1 = 0.f, m2 = 0.f, m3 = 0.f;

            // u-dot (operands prefetched 2 steps ago, likely SGPR-resident)
            {
                const float4 u0 = ub[j & 1][0], u1 = ub[j & 1][1];
                const float4 u2 = ub[j & 1][2], u3 = ub[j & 1][3];
                m0 = fmaf(Crow[ 0], u0.x, m0); m1 = fmaf(Crow[ 1], u0.y, m1);
                m2 = fmaf(Crow[ 2], u0.z, m2); m3 = fmaf(Crow[ 3], u0.w, m3);
                m0 = fmaf(Crow[ 4], u1.x, m0); m1 = fmaf(Crow[ 5], u1.y, m1);
                m2 = fmaf(Crow[ 6], u1.z, m2); m3 = fmaf(Crow[ 7], u1.w, m3);
                m0 = fmaf(Crow[ 8], u2.x, m0); m1 = fmaf(Crow[ 9], u2.y, m1);
                m2 = fmaf(Crow[10], u2.z, m2); m3 = fmaf(Crow[11], u2.w, m3);
                m0 = fmaf(Crow[12], u3.x, m0); m1 = fmaf(Crow[13], u3.y, m1);
                m2 = fmaf(Crow[14], u3.z, m2); m3 = fmaf(Crow[15], u3.w, m3);
            }

            // refill prefetch (clamped at tail; values unused then)
            {
                const int tu = (t + 2 < TT) ? (t + 2) : (TT - 1);
                #pragma unroll
                for (int q = 0; q < 4; ++q) ub[j & 1][q] = pu[(size_t)tu * su4 + q];
                const int tn = (t + 8 < TT) ? (t + 8) : (TT - 1);
                nzb[j] = pnz[(size_t)tn * snz];
            }

            // W-dot: broadcast relu(z) through SGPRs via readlane
            #pragma unroll
            for (int c = 0; c < DZ; c += 8) {
                const float s0 = __int_as_float(__builtin_amdgcn_readlane(rzb, c + 0));
                const float s1 = __int_as_float(__builtin_amdgcn_readlane(rzb, c + 1));
                const float s2 = __int_as_float(__builtin_amdgcn_readlane(rzb, c + 2));
                const float s3 = __int_as_float(__builtin_amdgcn_readlane(rzb, c + 3));
                const float s4 = __int_as_float(__builtin_amdgcn_readlane(rzb, c + 4));
                const float s5 = __int_as_float(__builtin_amdgcn_readlane(rzb, c + 5));
                const float s6 = __int_as_float(__builtin_amdgcn_readlane(rzb, c + 6));
                const float s7 = __int_as_float(__builtin_amdgcn_readlane(rzb, c + 7));
                m0 = fmaf(Wrow[c + 0], s0, m0);
                m1 = fmaf(Wrow[c + 1], s1, m1);
                m2 = fmaf(Wrow[c + 2], s2, m2);
                m3 = fmaf(Wrow[c + 3], s3, m3);
                m0 = fmaf(Wrow[c + 4], s4, m0);
                m1 = fmaf(Wrow[c + 5], s5, m1);
                m2 = fmaf(Wrow[c + 6], s6, m2);
                m3 = fmaf(Wrow[c + 7], s7, m3);
            }

            // z_{t+1} = mu + nz*q
            zl = fmaf(vnz, qv, (m0 + m1) + (m2 + m3));
        }
    }
}

// ---------------- Phase 2: x emission (fully parallel) ----------------
// Lanes 0-31 -> row r, lanes 32-63 -> row r+1; each lane computes one
// x[row, p] = sum_k z[row,k]*B[p,k] + nx[row,p]*r[p] over all 64 k.
// nx-load and x-store are single coalesced 256B wave transactions; z reads
// are half-wave broadcasts. B/R staged via LDS -> register-resident.
__global__ __launch_bounds__(256, 4) void plrnn_x_kernel(
    const float* __restrict__ z,    // (T*N, 64)
    const float* __restrict__ nx,   // (T*N, 32)
    const float* __restrict__ Bm,   // (32, 64)
    const float* __restrict__ R,    // (32,)
    float* __restrict__ xo)         // (T*N, 32)
{
    const int tid  = threadIdx.x;
    const int lane = tid & 63;
    const int p    = lane & 31;
    const int half = lane >> 5;

    __shared__ float Bl[DX][DZ + 4];
    __shared__ float Rl[DX];
    {
        const int r = tid >> 3;          // 0..31, 8 threads/row
        const int c = (tid & 7) * 8;     // 8 floats each
        #pragma unroll
        for (int k = 0; k < 8; ++k) Bl[r][c + k] = Bm[r * DZ + c + k];
        if (tid < DX) Rl[tid] = R[tid];
    }
    __syncthreads();

    float Brow[DZ];
    #pragma unroll
    for (int k = 0; k < DZ; ++k) Brow[k] = Bl[p][k];
    const float rv = softplus_eps(Rl[p]);

    const int gw   = blockIdx.x * 4 + (tid >> 6);   // global wave id (8192)
    const int base = gw * 128;                      // 128 rows per wave

    for (int i = 0; i < 128; i += 2) {
        const int r0 = base + i;
        const float4* zr = (const float4*)(z + (size_t)(r0 + half) * DZ);
        const float  vnx = nx[(size_t)r0 * DX + lane];   // rows r0,r0+1 coalesced

        float a0 = 0.f, a1 = 0.f, a2 = 0.f, a3 = 0.f;
        #pragma unroll
        for (int c = 0; c < 16; c += 4) {
            const float4 x0 = zr[c + 0];
            const float4 x1 = zr[c + 1];
            const float4 x2 = zr[c + 2];
            const float4 x3 = zr[c + 3];
            a0 = fmaf(Brow[4*c + 0], x0.x, a0);
            a1 = fmaf(Brow[4*c + 1], x0.y, a1);
            a2 = fmaf(Brow[4*c + 2], x0.z, a2);
            a3 = fmaf(Brow[4*c + 3], x0.w, a3);
            a0 = fmaf(Brow[4*c + 4], x1.x, a0);
            a1 = fmaf(Brow[4*c + 5], x1.y, a1);
            a2 = fmaf(Brow[4*c + 6], x1.z, a2);
            a3 = fmaf(Brow[4*c + 7], x1.w, a3);
            a0 = fmaf(Brow[4*c + 8], x2.x, a0);
            a1 = fmaf(Brow[4*c + 9], x2.y, a1);
            a2 = fmaf(Brow[4*c +10], x2.z, a2);
            a3 = fmaf(Brow[4*c +11], x2.w, a3);
            a0 = fmaf(Brow[4*c +12], x3.x, a0);
            a1 = fmaf(Brow[4*c +13], x3.y, a1);
            a2 = fmaf(Brow[4*c +14], x3.z, a2);
            a3 = fmaf(Brow[4*c +15], x3.w, a3);
        }
        xo[(size_t)r0 * DX + lane] = fmaf(vnx, rv, (a0 + a1) + (a2 + a3));
    }
}

extern "C" void kernel_launch(void* const* d_in, const int* in_sizes, int n_in,
                              void* d_out, int out_size, void* d_ws, size_t ws_size,
                              hipStream_t stream) {
    const float* u_  = (const float*)d_in[0];
    const float* z0_ = (const float*)d_in[1];
    const float* nz_ = (const float*)d_in[2];
    const float* nx_ = (const float*)d_in[3];
    const float* AW_ = (const float*)d_in[4];
    const float* C_  = (const float*)d_in[5];
    const float* B_  = (const float*)d_in[6];
    const float* Q_  = (const float*)d_in[7];
    const float* R_  = (const float*)d_in[8];

    float* zo = (float*)d_out;                 // (T,N,64) first
    float* xo = zo + (size_t)TT * NS * DZ;     // then (T,N,32)

    hipLaunchKernelGGL(plrnn_z_kernel, dim3(NS / 4), dim3(256), 0, stream,
                       u_, z0_, nz_, AW_, C_, Q_, zo);
    hipLaunchKernelGGL(plrnn_x_kernel, dim3(2048), dim3(256), 0, stream,
                       zo, nx_, B_, R_, xo);
}

// Round 6
// 935.430 us; speedup vs baseline: 1.7251x; 1.7251x over previous
//
#include <hip/hip_runtime.h>

#define DZ 64
#define DX 32
#define DS 16
#define TT 1024
#define NS 1024

__device__ __forceinline__ float softplus_eps(float x) {
    // jax.nn.softplus = max(x,0) + log1p(exp(-|x|)); +1e-6
    return fmaxf(x, 0.f) + log1pf(expf(-fabsf(x))) + 1e-6f;
}

// Fused PLRNN rollout: z-chain AND x-emission in one kernel.
// 1024 waves, one per sim, lane = z-dim. Per step, raw z is broadcast via
// v_readlane -> SGPRs; each k feeds BOTH the relu W-dot (v_max + fma) and
// the raw x-dot (fma with SGPR operand). No broadcast GLOBAL loads (R5's
// phase-2 9x HBM over-fetch), no z round-trip through HBM, no runtime-
// indexed register arrays (R5 scratch bug). Weights staged via LDS so the
// per-lane rows are ds_read-sourced -> not rematerializable -> VGPR-resident.
__global__ __launch_bounds__(256, 1) void plrnn_fused_kernel(
    const float* __restrict__ u,   // (T, N, 16)
    const float* __restrict__ z0,  // (N, 64)
    const float* __restrict__ nz,  // (T, N, 64)
    const float* __restrict__ nx,  // (T, N, 32)
    const float* __restrict__ AW,  // (64, 64)
    const float* __restrict__ Cm,  // (64, 16)
    const float* __restrict__ Bm,  // (32, 64)
    const float* __restrict__ Q,   // (64,)
    const float* __restrict__ R,   // (32,)
    float* __restrict__ zo,        // (T, N, 64)
    float* __restrict__ xo)        // (T, N, 32)
{
    const int tid  = threadIdx.x;
    const int lane = tid & 63;
    const int wv   = tid >> 6;
    const int p    = lane & 31;
    const int sim  = __builtin_amdgcn_readfirstlane((int)((blockIdx.x << 2) | wv));

    __shared__ float AWl[DZ][DZ + 4];
    __shared__ float Cl[DZ][DS + 4];
    __shared__ float Bl[DX][DZ + 4];
    __shared__ float Ql[DZ];
    __shared__ float Rl[DX];

    {   // one-time stage: AW 16/thr, C 4/thr, B 8/thr
        const int r = tid >> 2;
        const int c = (tid & 3) * 16;
        #pragma unroll
        for (int k = 0; k < 16; ++k) AWl[r][c + k] = AW[r * DZ + c + k];
        const int cc = (tid & 3) * 4;
        #pragma unroll
        for (int k = 0; k < 4; ++k) Cl[r][cc + k] = Cm[r * DS + cc + k];
        const int br = tid >> 3;            // 0..31
        const int bc = (tid & 7) * 8;
        #pragma unroll
        for (int k = 0; k < 8; ++k) Bl[br][bc + k] = Bm[br * DZ + bc + k];
        if (tid < DZ) Ql[tid] = Q[tid];
        if (tid < DX) Rl[tid] = R[tid];
    }
    __syncthreads();

    // per-lane weights -> VGPRs. ONLY compile-time indices (R5 scratch bug:
    // Wrow[lane] runtime index demoted the array to scratch).
    float Wrow[DZ];
    float Ad = 0.f;
    #pragma unroll
    for (int k = 0; k < DZ; ++k) {
        const float w = AWl[lane][k];
        Wrow[k] = (k == lane) ? 0.f : w;    // zero diagonal
        Ad      = (k == lane) ? w   : Ad;   // capture diagonal
    }
    float Crow[DS];
    #pragma unroll
    for (int s = 0; s < DS; ++s) Crow[s] = Cl[lane][s];
    float Brow[DZ];
    #pragma unroll
    for (int k = 0; k < DZ; ++k) Brow[k] = Bl[p][k];
    const float qv = softplus_eps(Ql[lane]);
    const float rv = softplus_eps(Rl[p]);

    float zl = z0[(size_t)sim * DZ + lane];

    const bool xl = (lane < DX);
    const float*  pnz = nz + (size_t)sim * DZ + lane;
    const float*  pnx = nx + (size_t)sim * DX + p;
    const float4* pu  = (const float4*)(u + (size_t)sim * DS);  // wave-uniform
    float*        pz  = zo + (size_t)sim * DZ + lane;
    float*        px  = xo + (size_t)sim * DX + p;

    const size_t snz = (size_t)NS * DZ;
    const size_t snx = (size_t)NS * DX;
    const size_t su4 = (size_t)NS * DS / 4;

    // prefetch: nz depth 8, nx depth 8 (half-wave), u depth 2
    float nzb[8], nxb[8];
    #pragma unroll
    for (int j = 0; j < 8; ++j) {
        nzb[j] = pnz[(size_t)j * snz];
        nxb[j] = xl ? pnx[(size_t)j * snx] : 0.f;
    }
    float4 ub[2][4];
    #pragma unroll
    for (int j = 0; j < 2; ++j)
        #pragma unroll
        for (int q = 0; q < 4; ++q) ub[j][q] = pu[(size_t)j * su4 + q];

    for (int t0 = 0; t0 < TT; t0 += 8) {
        #pragma unroll
        for (int j = 0; j < 8; ++j) {
            const int t = t0 + j;
            const float vnz = nzb[j];
            const float vnx = nxb[j];

            // emit z_t (carry BEFORE update; z[0] == z0)
            pz[(size_t)t * snz] = zl;

            const int zraw = __float_as_int(zl);

            float m0 = Ad * zl, m1 = 0.f, m2 = 0.f, m3 = 0.f;
            float xa0 = 0.f, xa1 = 0.f, xa2 = 0.f, xa3 = 0.f;

            // u-dot (prefetched 2 steps ago)
            {
                const float4 u0 = ub[j & 1][0], u1 = ub[j & 1][1];
                const float4 u2 = ub[j & 1][2], u3 = ub[j & 1][3];
                m0 = fmaf(Crow[ 0], u0.x, m0); m1 = fmaf(Crow[ 1], u0.y, m1);
                m2 = fmaf(Crow[ 2], u0.z, m2); m3 = fmaf(Crow[ 3], u0.w, m3);
                m0 = fmaf(Crow[ 4], u1.x, m0); m1 = fmaf(Crow[ 5], u1.y, m1);
                m2 = fmaf(Crow[ 6], u1.z, m2); m3 = fmaf(Crow[ 7], u1.w, m3);
                m0 = fmaf(Crow[ 8], u2.x, m0); m1 = fmaf(Crow[ 9], u2.y, m1);
                m2 = fmaf(Crow[10], u2.z, m2); m3 = fmaf(Crow[11], u2.w, m3);
                m0 = fmaf(Crow[12], u3.x, m0); m1 = fmaf(Crow[13], u3.y, m1);
                m2 = fmaf(Crow[14], u3.z, m2); m3 = fmaf(Crow[15], u3.w, m3);
            }

            // refill prefetch (clamped at tail; values unused then)
            {
                const int tu = (t + 2 < TT) ? (t + 2) : (TT - 1);
                #pragma unroll
                for (int q = 0; q < 4; ++q) ub[j & 1][q] = pu[(size_t)tu * su4 + q];
                const int tn = (t + 8 < TT) ? (t + 8) : (TT - 1);
                nzb[j] = pnz[(size_t)tn * snz];
                nxb[j] = xl ? pnx[(size_t)tn * snx] : 0.f;
            }

            // combined W-dot (relu) + x-dot (raw), z broadcast via SGPRs.
            // chunks of 16 readlanes to bound SGPR pressure.
            #pragma unroll
            for (int c = 0; c < DZ; c += 16) {
                int sg[16];
                #pragma unroll
                for (int i = 0; i < 16; ++i)
                    sg[i] = __builtin_amdgcn_readlane(zraw, c + i);
                #pragma unroll
                for (int i = 0; i < 16; ++i) {
                    const float zr = __int_as_float(sg[i]);
                    const float za = fmaxf(zr, 0.f);        // relu
                    const int k = c + i;
                    // rotate accumulator chains
                    if ((i & 3) == 0) { m0 = fmaf(Wrow[k], za, m0); xa0 = fmaf(Brow[k], zr, xa0); }
                    if ((i & 3) == 1) { m1 = fmaf(Wrow[k], za, m1); xa1 = fmaf(Brow[k], zr, xa1); }
                    if ((i & 3) == 2) { m2 = fmaf(Wrow[k], za, m2); xa2 = fmaf(Brow[k], zr, xa2); }
                    if ((i & 3) == 3) { m3 = fmaf(Wrow[k], za, m3); xa3 = fmaf(Brow[k], zr, xa3); }
                }
            }

            // x_t = z_t @ B.T + nx*r  (both halves computed it; half stores)
            const float xs = (xa0 + xa1) + (xa2 + xa3);
            if (xl) px[(size_t)t * snx] = fmaf(vnx, rv, xs);

            // z_{t+1} = mu + nz*q
            zl = fmaf(vnz, qv, (m0 + m1) + (m2 + m3));
        }
    }
}

extern "C" void kernel_launch(void* const* d_in, const int* in_sizes, int n_in,
                              void* d_out, int out_size, void* d_ws, size_t ws_size,
                              hipStream_t stream) {
    const float* u_  = (const float*)d_in[0];
    const float* z0_ = (const float*)d_in[1];
    const float* nz_ = (const float*)d_in[2];
    const float* nx_ = (const float*)d_in[3];
    const float* AW_ = (const float*)d_in[4];
    const float* C_  = (const float*)d_in[5];
    const float* B_  = (const float*)d_in[6];
    const float* Q_  = (const float*)d_in[7];
    const float* R_  = (const float*)d_in[8];

    float* zo = (float*)d_out;                 // (T,N,64) first
    float* xo = zo + (size_t)TT * NS * DZ;     // then (T,N,32)

    hipLaunchKernelGGL(plrnn_fused_kernel, dim3(NS / 4), dim3(256), 0, stream,
                       u_, z0_, nz_, nx_, AW_, C_, B_, Q_, R_, zo, xo);
}

// Round 8
// 513.340 us; speedup vs baseline: 3.1435x; 1.8222x over previous
//
#include <hip/hip_runtime.h>

#define DZ 64
#define DX 32
#define DS 16
#define TT 1024
#define NS 1024

// LDS layout (floats). Staging region is CLOBBERED by the per-step
// broadcast arrays: weight re-reads from LDS become illegal after the
// first loop store -> weights MUST stay in registers.
#define AW_B 0                    // 64 rows * 65
#define C_B  (AW_B + DZ * (DZ + 1))      // 64 * 17
#define B_B  (C_B + DZ * (DS + 1))       // 32 * 65
#define SMEM_FLOATS (B_B + DX * (DZ + 1))
// runtime arrays overlap the staging region (intentional aliasing):
#define ZR_B 0                    // raw z     [4][64]
#define ZA_B 1024                 // relu z    [4][64]
#define U_B  2048                 // u         [4][16]

__device__ __forceinline__ float softplus_eps(float x) {
    // jax.nn.softplus = max(x,0) + log1p(exp(-|x|)); +1e-6
    return fmaxf(x, 0.f) + log1pf(expf(-fabsf(x))) + 1e-6f;
}

__global__ __launch_bounds__(256, 1) void plrnn_fused_kernel(
    const float* __restrict__ u,   // (T, N, 16)
    const float* __restrict__ z0,  // (N, 64)
    const float* __restrict__ nz,  // (T, N, 64)
    const float* __restrict__ nx,  // (T, N, 32)
    const float* __restrict__ AW,  // (64, 64)
    const float* __restrict__ Cm,  // (64, 16)
    const float* __restrict__ Bm,  // (32, 64)
    const float* __restrict__ Q,   // (64,)
    const float* __restrict__ R,   // (32,)
    float* __restrict__ zo,        // (T, N, 64)
    float* __restrict__ xo)        // (T, N, 32)
{
    const int tid  = threadIdx.x;
    const int lane = tid & 63;
    const int wv   = tid >> 6;
    const int p    = lane & 31;          // x output row
    const int kb   = (lane >> 5) << 5;   // k-half base: 0 or 32
    const int sim  = __builtin_amdgcn_readfirstlane((int)((blockIdx.x << 2) | wv));

    __shared__ float smem[SMEM_FLOATS];

    {   // one-time stage: AW 16/thr, C 4/thr, B 8/thr
        const int r = tid >> 2;
        const int c = (tid & 3) * 16;
        #pragma unroll
        for (int k = 0; k < 16; ++k) smem[AW_B + r * (DZ + 1) + c + k] = AW[r * DZ + c + k];
        const int cc = (tid & 3) * 4;
        #pragma unroll
        for (int k = 0; k < 4; ++k) smem[C_B + r * (DS + 1) + cc + k] = Cm[r * DS + cc + k];
        const int br = tid >> 3;
        const int bc = (tid & 7) * 8;
        #pragma unroll
        for (int k = 0; k < 8; ++k) smem[B_B + br * (DZ + 1) + bc + k] = Bm[br * DZ + bc + k];
    }
    __syncthreads();

    // per-lane weights -> registers (compile-time indices only)
    float Wrow[DZ];
    float Ad = 0.f;
    #pragma unroll
    for (int k = 0; k < DZ; ++k) {
        const float w = smem[AW_B + lane * (DZ + 1) + k];
        Wrow[k] = (k == lane) ? 0.f : w;    // zero diagonal
        Ad      = (k == lane) ? w   : Ad;   // capture diagonal
    }
    float Crow[DS];
    #pragma unroll
    for (int s = 0; s < DS; ++s) Crow[s] = smem[C_B + lane * (DS + 1) + s];
    float Brow[32];                          // B[p][kb .. kb+31] (split-k)
    #pragma unroll
    for (int k = 0; k < 32; ++k) Brow[k] = smem[B_B + p * (DZ + 1) + kb + k];

    const float qv = softplus_eps(Q[lane]);
    const float rv = softplus_eps(R[p]);

    __syncthreads();   // all waves done reading staged weights before clobber

    float zl = z0[(size_t)sim * DZ + lane];

    const size_t snz = (size_t)NS * DZ;
    const size_t snx = (size_t)NS * DX;
    const size_t su  = (size_t)NS * DS;

    const float* pnz = nz + (size_t)sim * DZ + lane;
    const float* pnx = nx + (size_t)sim * DX + p;          // hi half dups low
    const float* puu = u  + (size_t)sim * DS + (lane & 15);
    float* pz = zo + (size_t)sim * DZ + lane;
    float* px = xo + (size_t)sim * DX + p;

    // prefetch depth 4, then running pointers (no per-step index muls)
    float nzb[4], nxb[4], ub[4];
    #pragma unroll
    for (int j = 0; j < 4; ++j) {
        nzb[j] = pnz[(size_t)j * snz];
        nxb[j] = pnx[(size_t)j * snx];
        ub[j]  = puu[(size_t)j * su];
    }
    const float* pnz_pf = pnz + 4 * snz;
    const float* pnx_pf = pnx + 4 * snx;
    const float* puu_pf = puu + 4 * su;

    float* lzr = &smem[ZR_B + wv * DZ];   // wave-private slices
    float* lza = &smem[ZA_B + wv * DZ];
    float* lup = &smem[U_B  + wv * DS];

    for (int t0 = 0; t0 < TT; t0 += 4) {
        #pragma unroll
        for (int j = 0; j < 4; ++j) {
            const int t = t0 + j;
            const float vnz = nzb[j];
            const float vnx = nxb[j];

            // publish step-t operands (CLOBBERS the weight staging region)
            lzr[lane] = zl;
            lza[lane] = fmaxf(zl, 0.f);     // relu ONCE per lane
            if (lane < DS) lup[lane] = ub[j];

            // emit z_t (carry BEFORE update; z[0] == z0)
            pz[0] = zl;

            float m0 = Ad * zl, m1 = 0.f, m2 = 0.f, m3 = 0.f;

            // u-dot: 4 broadcast ds_read_b128
            #pragma unroll
            for (int s4 = 0; s4 < 4; ++s4) {
                const float4 uu = *(const float4*)&lup[4 * s4];
                m0 = fmaf(Crow[4*s4+0], uu.x, m0);
                m1 = fmaf(Crow[4*s4+1], uu.y, m1);
                m2 = fmaf(Crow[4*s4+2], uu.z, m2);
                m3 = fmaf(Crow[4*s4+3], uu.w, m3);
            }

            // refill prefetch. Pointer rests on the LAST valid step (TT-1):
            // advance only while the NEXT prefetch target (t+5) is < TT.
            // (R7 crash: ok=(t+4<TT) advanced to step TT at t=TT-5, then
            //  t>=TT-4 dereferenced one step past the array -> device fault.)
            {
                const bool ok = (t + 5) < TT;
                nzb[j] = pnz_pf[0];
                nxb[j] = pnx_pf[0];
                ub[j]  = puu_pf[0];
                pnz_pf = ok ? (pnz_pf + snz) : pnz_pf;
                pnx_pf = ok ? (pnx_pf + snx) : pnx_pf;
                puu_pf = ok ? (puu_pf + su ) : puu_pf;
            }

            // W-dot: 16 broadcast ds_read_b128 of relu(z)
            #pragma unroll
            for (int k4 = 0; k4 < 16; ++k4) {
                const float4 zz = *(const float4*)&lza[4 * k4];
                m0 = fmaf(Wrow[4*k4+0], zz.x, m0);
                m1 = fmaf(Wrow[4*k4+1], zz.y, m1);
                m2 = fmaf(Wrow[4*k4+2], zz.z, m2);
                m3 = fmaf(Wrow[4*k4+3], zz.w, m3);
            }

            // x-dot: split-k (each half-wave does 32 of 64 k's)
            float xa0 = 0.f, xa1 = 0.f;
            #pragma unroll
            for (int k4 = 0; k4 < 8; ++k4) {
                const float4 zz = *(const float4*)&lzr[kb + 4 * k4];
                xa0 = fmaf(Brow[4*k4+0], zz.x, xa0);
                xa1 = fmaf(Brow[4*k4+1], zz.y, xa1);
                xa0 = fmaf(Brow[4*k4+2], zz.z, xa0);
                xa1 = fmaf(Brow[4*k4+3], zz.w, xa1);
            }
            float xs = xa0 + xa1;
            xs += __shfl_xor(xs, 32);       // combine k-halves
            if (lane < DX) px[0] = fmaf(vnx, rv, xs);

            pz += snz;
            px += snx;

            // z_{t+1} = mu + nz*q
            zl = fmaf(vnz, qv, (m0 + m1) + (m2 + m3));
        }
    }
}

extern "C" void kernel_launch(void* const* d_in, const int* in_sizes, int n_in,
                              void* d_out, int out_size, void* d_ws, size_t ws_size,
                              hipStream_t stream) {
    const float* u_  = (const float*)d_in[0];
    const float* z0_ = (const float*)d_in[1];
    const float* nz_ = (const float*)d_in[2];
    const float* nx_ = (const float*)d_in[3];
    const float* AW_ = (const float*)d_in[4];
    const float* C_  = (const float*)d_in[5];
    const float* B_  = (const float*)d_in[6];
    const float* Q_  = (const float*)d_in[7];
    const float* R_  = (const float*)d_in[8];

    float* zo = (float*)d_out;                 // (T,N,64) first
    float* xo = zo + (size_t)TT * NS * DZ;     // then (T,N,32)

    hipLaunchKernelGGL(plrnn_fused_kernel, dim3(NS / 4), dim3(256), 0, stream,
                       u_, z0_, nz_, nx_, AW_, C_, B_, Q_, R_, zo, xo);
}